// Round 1
// baseline (208.431 us; speedup 1.0000x reference)
//
#include <hip/hip_runtime.h>
#include <math.h>

#define INDIM 10
#define DIM 32
#define LAYERS 4
#define MODES 17

// ---------------------------------------------------------------------------
// Precompute: fold rfft -> complex mode-mix -> irfft into a real 32x32 matrix
// per layer, added to proj_W.  Wc[l] = M_l + proj_W[l].
//
//   M[n][n'] = (1/32) * sum_{o=0..16} f_o * Re( y_o(n) * e^{+2pi i o n'/32} )
//   y_o(n)   = sum_{m=0..16} e^{-2pi i m n/32} * (wr[m][o] + i wi[m][o])
//   f_o = 1 for o in {0,16}, else 2   (C2R ignores Im at DC/Nyquist)
// ---------------------------------------------------------------------------
__global__ void fno_precompute(const float* __restrict__ wr,
                               const float* __restrict__ wi,
                               const float* __restrict__ projW,
                               float* __restrict__ wc) {
    const int l  = blockIdx.x;        // layer
    const int tx = threadIdx.x;       // 1024 threads
    const int j  = tx & 31;           // output position n'
    const int n  = tx >> 5;           // input position n

    __shared__ float ct[32], st[32];
    if (tx < 32) {
        float ang = (2.0f * 3.14159265358979323846f / 32.0f) * (float)tx;
        ct[tx] = cosf(ang);
        st[tx] = sinf(ang);
    }
    __syncthreads();

    const float* lwr = wr + l * MODES * MODES;
    const float* lwi = wi + l * MODES * MODES;

    float acc = 0.0f;
    for (int o = 0; o < MODES; ++o) {
        float re = 0.0f, im = 0.0f;
        for (int m = 0; m < MODES; ++m) {
            int t = (m * n) & 31;
            float c = ct[t], s = st[t];
            float a = lwr[m * MODES + o];
            float b = lwi[m * MODES + o];
            // e^{-i*theta} * (a + i b) = (c*a + s*b) + i*(c*b - s*a)
            re += c * a + s * b;
            im += c * b - s * a;
        }
        int t2 = (o * j) & 31;
        float f = (o == 0 || o == 16) ? 1.0f : 2.0f;
        // Re( (re + i*im) * e^{+i*theta2} ) = re*cos - im*sin
        acc += f * (re * ct[t2] - im * st[t2]);
    }
    acc *= (1.0f / 32.0f);
    wc[(l * DIM + n) * DIM + j] = acc + projW[(l * DIM + n) * DIM + j];
}

// ---------------------------------------------------------------------------
// Main fused kernel: one thread = one batch row.
// stem (10->32), 4 x [dense 32x32 + bias + silu], head (32->10).
// All weights staged in LDS (broadcast reads, conflict-free).
// h[32]/acc[32] live in VGPRs with fully static indexing.
// ---------------------------------------------------------------------------
__global__ __launch_bounds__(256) void fno_main(
    const float* __restrict__ x,
    const float* __restrict__ stemW,   // [10][32]
    const float* __restrict__ stemB,   // [32]
    const float* __restrict__ wc,      // [4][32][32] combined
    const float* __restrict__ projB,   // [4][32]
    const float* __restrict__ headW,   // [32][10]
    const float* __restrict__ headB,   // [10]
    float* __restrict__ out,
    int nrows) {
    __shared__ float sW[INDIM * DIM];            // 320
    __shared__ float sB[DIM];                    // 32
    __shared__ float sWc[LAYERS * DIM * DIM];    // 4096
    __shared__ float sPb[LAYERS * DIM];          // 128
    __shared__ float sHW[DIM * INDIM];           // 320
    __shared__ float sHb[INDIM];                 // 10

    const int tx = threadIdx.x;
    for (int i = tx; i < INDIM * DIM; i += 256)      sW[i]  = stemW[i];
    if (tx < DIM)                                    sB[tx] = stemB[tx];
    for (int i = tx; i < LAYERS * DIM * DIM; i += 256) sWc[i] = wc[i];
    for (int i = tx; i < LAYERS * DIM; i += 256)     sPb[i] = projB[i];
    for (int i = tx; i < DIM * INDIM; i += 256)      sHW[i] = headW[i];
    if (tx < INDIM)                                  sHb[tx] = headB[tx];
    __syncthreads();

    const long row = (long)blockIdx.x * 256 + tx;
    if (row >= nrows) return;

    // ---- load input row ----
    float xr[INDIM];
    const float* xp = x + row * INDIM;
#pragma unroll
    for (int k = 0; k < INDIM; ++k) xr[k] = xp[k];

    // ---- stem ----
    float h[DIM];
#pragma unroll
    for (int j = 0; j < DIM; ++j) {
        float a = sB[j];
#pragma unroll
        for (int k = 0; k < INDIM; ++k) a += xr[k] * sW[k * DIM + j];
        h[j] = a;
    }

    // ---- 4 fused FNO layers ----
    for (int l = 0; l < LAYERS; ++l) {
        const float* wl = &sWc[l * DIM * DIM];
        const float* bl = &sPb[l * DIM];
        float acc[DIM];
#pragma unroll
        for (int j = 0; j < DIM; ++j) acc[j] = bl[j];
#pragma unroll
        for (int k = 0; k < DIM; ++k) {
            float hk = h[k];
#pragma unroll
            for (int j = 0; j < DIM; ++j) acc[j] += hk * wl[k * DIM + j];
        }
#pragma unroll
        for (int j = 0; j < DIM; ++j) {
            float v = acc[j];
            h[j] = v / (1.0f + __expf(-v));   // silu
        }
    }

    // ---- head ----
    float* op = out + row * INDIM;
#pragma unroll
    for (int o = 0; o < INDIM; ++o) {
        float a = sHb[o];
#pragma unroll
        for (int k = 0; k < DIM; ++k) a += h[k] * sHW[k * INDIM + o];
        op[o] = a;
    }
}

extern "C" void kernel_launch(void* const* d_in, const int* in_sizes, int n_in,
                              void* d_out, int out_size, void* d_ws, size_t ws_size,
                              hipStream_t stream) {
    const float* x      = (const float*)d_in[0];
    const float* stemW  = (const float*)d_in[1];
    const float* stemB  = (const float*)d_in[2];
    const float* fno_wr = (const float*)d_in[3];
    const float* fno_wi = (const float*)d_in[4];
    const float* projW  = (const float*)d_in[5];
    const float* projB  = (const float*)d_in[6];
    const float* headW  = (const float*)d_in[7];
    const float* headB  = (const float*)d_in[8];
    float* out = (float*)d_out;
    float* wc  = (float*)d_ws;   // [4][32][32] combined spectral+proj weights

    const int nrows = in_sizes[0] / INDIM;

    fno_precompute<<<LAYERS, 1024, 0, stream>>>(fno_wr, fno_wi, projW, wc);

    const int nblk = (nrows + 255) / 256;
    fno_main<<<nblk, 256, 0, stream>>>(x, stemW, stemB, wc, projB,
                                       headW, headB, out, nrows);
}

// Round 3
// 121.022 us; speedup vs baseline: 1.7223x; 1.7223x over previous
//
#include <hip/hip_runtime.h>
#include <math.h>

#define INDIM 10
#define DIM 32
#define LAYERS 4
#define MODES 17
#define NT 4          // 16-row tiles per wave
#define LDS_STRIDE 40 // f16 elems per row (32 used + 8 pad -> 80B, kills bank aliasing)

typedef _Float16 f16;
typedef _Float16 f16x8 __attribute__((ext_vector_type(8)));
typedef float f32x4 __attribute__((ext_vector_type(4)));

// ---------------------------------------------------------------------------
// Fold rfft -> complex mode-mix -> irfft into a real 32x32 matrix per layer,
// added to proj_W.  Wc[l] = M_l + proj_W[l].  (verified in round 1)
// ---------------------------------------------------------------------------
__global__ void fno_precompute(const float* __restrict__ wr,
                               const float* __restrict__ wi,
                               const float* __restrict__ projW,
                               float* __restrict__ wc) {
    const int l  = blockIdx.x;
    const int tx = threadIdx.x;
    const int j  = tx & 31;
    const int n  = tx >> 5;

    __shared__ float ct[32], st[32];
    if (tx < 32) {
        float ang = (2.0f * 3.14159265358979323846f / 32.0f) * (float)tx;
        ct[tx] = cosf(ang);
        st[tx] = sinf(ang);
    }
    __syncthreads();

    const float* lwr = wr + l * MODES * MODES;
    const float* lwi = wi + l * MODES * MODES;

    float acc = 0.0f;
    for (int o = 0; o < MODES; ++o) {
        float re = 0.0f, im = 0.0f;
        for (int m = 0; m < MODES; ++m) {
            int t = (m * n) & 31;
            float c = ct[t], s = st[t];
            float a = lwr[m * MODES + o];
            float b = lwi[m * MODES + o];
            re += c * a + s * b;
            im += c * b - s * a;
        }
        int t2 = (o * j) & 31;
        float f = (o == 0 || o == 16) ? 1.0f : 2.0f;
        acc += f * (re * ct[t2] - im * st[t2]);
    }
    acc *= (1.0f / 32.0f);
    wc[(l * DIM + n) * DIM + j] = acc + projW[(l * DIM + n) * DIM + j];
}

// ---------------------------------------------------------------------------
// MFMA pipeline: per wave, per 16-row tile:
//   stem   : A = x (K=10 padded to 32), B = stemW    -> 2 MFMA
//   layer l: A = h  (LDS roundtrip),    B = Wc[l]    -> 2 MFMA + silu
//   head   : A = h4,                    B = headW    -> 1 MFMA
// Fragment conventions (m89-verified D; A/B consistent-k argument):
//   A: row = lane&15, k = 8*(lane>>4)+e      B: col = lane&15, k = same
//   D: col = lane&15, row = 4*(lane>>4)+reg
// ---------------------------------------------------------------------------
__global__ __launch_bounds__(256) void fno_main(
    const float* __restrict__ x,
    const float* __restrict__ stemW,   // [10][32]
    const float* __restrict__ stemB,   // [32]
    const float* __restrict__ wc,      // [4][32][32]
    const float* __restrict__ projB,   // [4][32]
    const float* __restrict__ headW,   // [32][10]
    const float* __restrict__ headB,   // [10]
    float* __restrict__ out,
    int nrows) {

    __shared__ __align__(16) f16 sh[4][16 * LDS_STRIDE];  // 1.25 KB per wave

    const int tid = threadIdx.x;
    const int w   = tid >> 6;
    const int ln  = tid & 63;
    const int c   = ln & 15;   // A-row / B-col / D-col
    const int g   = ln >> 4;   // k-group
    f16* shw = &sh[w][0];

    // ---- weight fragments, held in VGPRs for the whole kernel ----
    f16x8 wf[2 * LAYERS];
#pragma unroll
    for (int l = 0; l < LAYERS; ++l) {
#pragma unroll
        for (int h = 0; h < 2; ++h) {
            f16x8 f;
#pragma unroll
            for (int e = 0; e < 8; ++e) {
                int k = 8 * g + e;
                f[e] = (f16)wc[(l * DIM + k) * DIM + 16 * h + c];
            }
            wf[2 * l + h] = f;
        }
    }
    f16x8 ws0, ws1;
#pragma unroll
    for (int e = 0; e < 8; ++e) {
        int k = 8 * g + e;
        float v0 = (k < INDIM) ? stemW[k * DIM + c] : 0.0f;
        float v1 = (k < INDIM) ? stemW[k * DIM + 16 + c] : 0.0f;
        ws0[e] = (f16)v0;
        ws1[e] = (f16)v1;
    }
    f16x8 wh;
#pragma unroll
    for (int e = 0; e < 8; ++e) {
        int k = 8 * g + e;
        float v = (c < INDIM) ? headW[k * INDIM + c] : 0.0f;
        wh[e] = (f16)v;
    }
    const float sb0 = stemB[c];
    const float sb1 = stemB[16 + c];
    float pb0[LAYERS], pb1[LAYERS];
#pragma unroll
    for (int l = 0; l < LAYERS; ++l) {
        pb0[l] = projB[l * DIM + c];
        pb1[l] = projB[l * DIM + 16 + c];
    }
    const float hb = (c < INDIM) ? headB[c] : 0.0f;

    const long blockRow0 = (long)blockIdx.x * (4 * NT * 16);

    for (int t = 0; t < NT; ++t) {
        const long rb = blockRow0 + (long)w * (NT * 16) + (long)t * 16;
        if (rb >= nrows) break;

        // ---- stem: A from x (f16), K padded 10->32 ----
        f16x8 ax;
#pragma unroll
        for (int e = 0; e < 8; ++e) {
            int k = 8 * g + e;
            float v = 0.0f;
            if (k < INDIM && rb + c < nrows) v = x[(rb + c) * INDIM + k];
            ax[e] = (f16)v;
        }
        f32x4 acc0 = {sb0, sb0, sb0, sb0};
        f32x4 acc1 = {sb1, sb1, sb1, sb1};
        f32x4 d0 = __builtin_amdgcn_mfma_f32_16x16x32_f16(ax, ws0, acc0, 0, 0, 0);
        f32x4 d1 = __builtin_amdgcn_mfma_f32_16x16x32_f16(ax, ws1, acc1, 0, 0, 0);

        // write h0 (stem has no activation)
#pragma unroll
        for (int r = 0; r < 4; ++r) {
            int row = 4 * g + r;
            shw[row * LDS_STRIDE + c]      = (f16)d0[r];
            shw[row * LDS_STRIDE + 16 + c] = (f16)d1[r];
        }

        // ---- 4 fused layers ----
#pragma unroll
        for (int l = 0; l < LAYERS; ++l) {
            f16x8 a = *(const f16x8*)&shw[c * LDS_STRIDE + g * 8];
            f32x4 b0 = {pb0[l], pb0[l], pb0[l], pb0[l]};
            f32x4 b1 = {pb1[l], pb1[l], pb1[l], pb1[l]};
            f32x4 e0 = __builtin_amdgcn_mfma_f32_16x16x32_f16(a, wf[2 * l],     b0, 0, 0, 0);
            f32x4 e1 = __builtin_amdgcn_mfma_f32_16x16x32_f16(a, wf[2 * l + 1], b1, 0, 0, 0);
#pragma unroll
            for (int r = 0; r < 4; ++r) {
                int row = 4 * g + r;
                float v0 = e0[r];
                float v1 = e1[r];
                v0 = v0 / (1.0f + __expf(-v0));
                v1 = v1 / (1.0f + __expf(-v1));
                shw[row * LDS_STRIDE + c]      = (f16)v0;
                shw[row * LDS_STRIDE + 16 + c] = (f16)v1;
            }
        }

        // ---- head ----
        f16x8 a = *(const f16x8*)&shw[c * LDS_STRIDE + g * 8];
        f32x4 hacc = {hb, hb, hb, hb};
        f32x4 dh = __builtin_amdgcn_mfma_f32_16x16x32_f16(a, wh, hacc, 0, 0, 0);
        if (c < INDIM) {
#pragma unroll
            for (int r = 0; r < 4; ++r) {
                long row = rb + 4 * g + r;
                if (row < nrows) out[row * INDIM + c] = dh[r];
            }
        }
    }
}

extern "C" void kernel_launch(void* const* d_in, const int* in_sizes, int n_in,
                              void* d_out, int out_size, void* d_ws, size_t ws_size,
                              hipStream_t stream) {
    const float* x      = (const float*)d_in[0];
    const float* stemW  = (const float*)d_in[1];
    const float* stemB  = (const float*)d_in[2];
    const float* fno_wr = (const float*)d_in[3];
    const float* fno_wi = (const float*)d_in[4];
    const float* projW  = (const float*)d_in[5];
    const float* projB  = (const float*)d_in[6];
    const float* headW  = (const float*)d_in[7];
    const float* headB  = (const float*)d_in[8];
    float* out = (float*)d_out;
    float* wcb = (float*)d_ws;

    const int nrows = in_sizes[0] / INDIM;

    fno_precompute<<<LAYERS, 1024, 0, stream>>>(fno_wr, fno_wi, projW, wcb);

    // rows per block = 4 waves * NT tiles * 16 rows = 256
    const int rows_per_block = 4 * NT * 16;
    const int nblk = (nrows + rows_per_block - 1) / rows_per_block;
    fno_main<<<nblk, 256, 0, stream>>>(x, stemW, stemB, wcb, projB,
                                       headW, headB, out, nrows);
}

// Round 4
// 75.721 us; speedup vs baseline: 2.7526x; 1.5983x over previous
//
#include <hip/hip_runtime.h>
#include <math.h>

#define INDIM 10
#define DIM 32
#define LAYERS 4
#define MODES 17
#define NT 4          // 16-row tiles per wave
#define LDS_STRIDE 40 // f16 elems per row (80B; read b128 16B-aligned; conflicts measured negligible)

// d_ws layout:
//   [0, 16384)        : wc f32 [4][32][32]
//   [16384, 27648)    : frag f16 [11][64][8]   (per-lane MFMA B/A fragments)
//   [27648, 30720)    : bias f32 [64][12]
#define WS_FRAG_OFF 16384
#define WS_BIAS_OFF 27648

typedef _Float16 f16;
typedef _Float16 f16x8 __attribute__((ext_vector_type(8)));
typedef float f32x4 __attribute__((ext_vector_type(4)));

// ---------------------------------------------------------------------------
// Fold rfft -> complex mode-mix -> irfft into a real 32x32 matrix per layer,
// added to proj_W.  Wc[l] = M_l + proj_W[l].  (verified round 1)
// ---------------------------------------------------------------------------
__global__ void fno_precompute(const float* __restrict__ wr,
                               const float* __restrict__ wi,
                               const float* __restrict__ projW,
                               float* __restrict__ wc) {
    const int l  = blockIdx.x;
    const int tx = threadIdx.x;
    const int j  = tx & 31;
    const int n  = tx >> 5;

    __shared__ float ct[32], st[32];
    if (tx < 32) {
        float ang = (2.0f * 3.14159265358979323846f / 32.0f) * (float)tx;
        ct[tx] = cosf(ang);
        st[tx] = sinf(ang);
    }
    __syncthreads();

    const float* lwr = wr + l * MODES * MODES;
    const float* lwi = wi + l * MODES * MODES;

    float acc = 0.0f;
    for (int o = 0; o < MODES; ++o) {
        float re = 0.0f, im = 0.0f;
        for (int m = 0; m < MODES; ++m) {
            int t = (m * n) & 31;
            float c = ct[t], s = st[t];
            float a = lwr[m * MODES + o];
            float b = lwi[m * MODES + o];
            re += c * a + s * b;
            im += c * b - s * a;
        }
        int t2 = (o * j) & 31;
        float f = (o == 0 || o == 16) ? 1.0f : 2.0f;
        acc += f * (re * ct[t2] - im * st[t2]);
    }
    acc *= (1.0f / 32.0f);
    wc[(l * DIM + n) * DIM + j] = acc + projW[(l * DIM + n) * DIM + j];
}

// ---------------------------------------------------------------------------
// Pack per-lane MFMA fragments + biases so the main kernel's preamble is a
// handful of coalesced dwordx4 loads instead of ~88 scattered scalar gathers.
// Fragment conventions (A: row=ln&15,k=8g+e | B: col=ln&15,k=8g+e | D: m89).
// frag f in [0,7]: layer weights wf[2l+h]; f=8,9: stemW halves; f=10: headW.
// ---------------------------------------------------------------------------
__global__ void fno_pack(const float* __restrict__ wc,
                         const float* __restrict__ stemW,
                         const float* __restrict__ headW,
                         const float* __restrict__ stemB,
                         const float* __restrict__ projB,
                         const float* __restrict__ headB,
                         f16* __restrict__ frag,
                         float* __restrict__ bias) {
    const int ln = threadIdx.x;  // 64
    const int c  = ln & 15;
    const int g  = ln >> 4;

#pragma unroll
    for (int l = 0; l < LAYERS; ++l)
#pragma unroll
        for (int h = 0; h < 2; ++h)
#pragma unroll
            for (int e = 0; e < 8; ++e) {
                int k = 8 * g + e;
                frag[((2 * l + h) * 64 + ln) * 8 + e] =
                    (f16)wc[(l * DIM + k) * DIM + 16 * h + c];
            }
#pragma unroll
    for (int e = 0; e < 8; ++e) {
        int k = 8 * g + e;
        frag[(8 * 64 + ln) * 8 + e]  = (f16)(k < INDIM ? stemW[k * DIM + c] : 0.0f);
        frag[(9 * 64 + ln) * 8 + e]  = (f16)(k < INDIM ? stemW[k * DIM + 16 + c] : 0.0f);
        frag[(10 * 64 + ln) * 8 + e] = (f16)(c < INDIM ? headW[k * INDIM + c] : 0.0f);
    }
    float* bl = bias + ln * 12;
    bl[0] = stemB[c];
    bl[1] = stemB[16 + c];
#pragma unroll
    for (int l = 0; l < LAYERS; ++l) {
        bl[2 + 2 * l]     = projB[l * DIM + c];
        bl[2 + 2 * l + 1] = projB[l * DIM + 16 + c];
    }
    bl[10] = (c < INDIM) ? headB[c] : 0.0f;
    bl[11] = 0.0f;
}

__device__ __forceinline__ float silu_f(float v) {
    // v * sigmoid(v); rcp is the 1-ulp v_rcp_f32 (avoids full-precision div seq)
    return v * __builtin_amdgcn_rcpf(1.0f + __expf(-v));
}

// ---------------------------------------------------------------------------
// Main MFMA pipeline, per wave per 16-row tile:
//   stem (2 MFMA) -> 4 x [LDS roundtrip + 2 MFMA + silu] -> head (1 MFMA)
// ---------------------------------------------------------------------------
__global__ __launch_bounds__(256) void fno_main(
    const float* __restrict__ x,
    const f16*  __restrict__ fragbuf,   // [11][64][8]
    const float* __restrict__ biasbuf,  // [64][12]
    float* __restrict__ out,
    int nrows) {

    __shared__ __align__(16) f16 sh[4][16 * LDS_STRIDE];

    const int tid = threadIdx.x;
    const int w   = tid >> 6;
    const int ln  = tid & 63;
    const int c   = ln & 15;
    const int g   = ln >> 4;
    f16* shw = &sh[w][0];

    // ---- preamble: coalesced fragment + bias loads ----
    const f16x8* fb = (const f16x8*)fragbuf;
    f16x8 wf[2 * LAYERS];
#pragma unroll
    for (int f = 0; f < 2 * LAYERS; ++f) wf[f] = fb[f * 64 + ln];
    const f16x8 ws0 = fb[8 * 64 + ln];
    const f16x8 ws1 = fb[9 * 64 + ln];
    const f16x8 wh  = fb[10 * 64 + ln];

    const float4* bb = (const float4*)(biasbuf + ln * 12);
    const float4 bv0 = bb[0];  // sb0, sb1, pb[0].lo, pb[0].hi
    const float4 bv1 = bb[1];  // pb[1].lo, pb[1].hi, pb[2].lo, pb[2].hi
    const float4 bv2 = bb[2];  // pb[3].lo, pb[3].hi, hb, pad
    const float sb0 = bv0.x, sb1 = bv0.y;
    const float pb0[LAYERS] = {bv0.z, bv1.x, bv1.z, bv2.x};
    const float pb1[LAYERS] = {bv0.w, bv1.y, bv1.w, bv2.y};
    const float hb = bv2.z;

    const long blockRow0 = (long)blockIdx.x * (4 * NT * 16);

#pragma unroll
    for (int t = 0; t < NT; ++t) {
        const long rb = blockRow0 + (long)w * (NT * 16) + (long)t * 16;

        // ---- stem A-frag: structured, aligned float2 loads ----
        f16x8 ax = {};
        const long xrow  = rb + c;
        const bool rowok = xrow < nrows;
        const float* xp  = x + xrow * INDIM;
        if (g == 0 && rowok) {
            float2 p0 = *(const float2*)(xp + 0);
            float2 p1 = *(const float2*)(xp + 2);
            float2 p2 = *(const float2*)(xp + 4);
            float2 p3 = *(const float2*)(xp + 6);
            ax[0] = (f16)p0.x; ax[1] = (f16)p0.y;
            ax[2] = (f16)p1.x; ax[3] = (f16)p1.y;
            ax[4] = (f16)p2.x; ax[5] = (f16)p2.y;
            ax[6] = (f16)p3.x; ax[7] = (f16)p3.y;
        } else if (g == 1 && rowok) {
            float2 p4 = *(const float2*)(xp + 8);
            ax[0] = (f16)p4.x; ax[1] = (f16)p4.y;
        }

        f32x4 acc0 = {sb0, sb0, sb0, sb0};
        f32x4 acc1 = {sb1, sb1, sb1, sb1};
        f32x4 d0 = __builtin_amdgcn_mfma_f32_16x16x32_f16(ax, ws0, acc0, 0, 0, 0);
        f32x4 d1 = __builtin_amdgcn_mfma_f32_16x16x32_f16(ax, ws1, acc1, 0, 0, 0);

#pragma unroll
        for (int r = 0; r < 4; ++r) {
            int row = 4 * g + r;
            shw[row * LDS_STRIDE + c]      = (f16)d0[r];
            shw[row * LDS_STRIDE + 16 + c] = (f16)d1[r];
        }

        // ---- 4 fused layers ----
#pragma unroll
        for (int l = 0; l < LAYERS; ++l) {
            f16x8 a = *(const f16x8*)&shw[c * LDS_STRIDE + g * 8];
            f32x4 b0 = {pb0[l], pb0[l], pb0[l], pb0[l]};
            f32x4 b1 = {pb1[l], pb1[l], pb1[l], pb1[l]};
            f32x4 e0 = __builtin_amdgcn_mfma_f32_16x16x32_f16(a, wf[2 * l],     b0, 0, 0, 0);
            f32x4 e1 = __builtin_amdgcn_mfma_f32_16x16x32_f16(a, wf[2 * l + 1], b1, 0, 0, 0);
#pragma unroll
            for (int r = 0; r < 4; ++r) {
                int row = 4 * g + r;
                shw[row * LDS_STRIDE + c]      = (f16)silu_f(e0[r]);
                shw[row * LDS_STRIDE + 16 + c] = (f16)silu_f(e1[r]);
            }
        }

        // ---- head ----
        f16x8 a = *(const f16x8*)&shw[c * LDS_STRIDE + g * 8];
        f32x4 hacc = {hb, hb, hb, hb};
        f32x4 dh = __builtin_amdgcn_mfma_f32_16x16x32_f16(a, wh, hacc, 0, 0, 0);
        if (c < INDIM) {
#pragma unroll
            for (int r = 0; r < 4; ++r) {
                long row = rb + 4 * g + r;
                if (row < nrows) out[row * INDIM + c] = dh[r];
            }
        }
    }
}

extern "C" void kernel_launch(void* const* d_in, const int* in_sizes, int n_in,
                              void* d_out, int out_size, void* d_ws, size_t ws_size,
                              hipStream_t stream) {
    const float* x      = (const float*)d_in[0];
    const float* stemW  = (const float*)d_in[1];
    const float* stemB  = (const float*)d_in[2];
    const float* fno_wr = (const float*)d_in[3];
    const float* fno_wi = (const float*)d_in[4];
    const float* projW  = (const float*)d_in[5];
    const float* projB  = (const float*)d_in[6];
    const float* headW  = (const float*)d_in[7];
    const float* headB  = (const float*)d_in[8];
    float* out = (float*)d_out;

    float* wcb  = (float*)d_ws;
    f16*   frag = (f16*)((char*)d_ws + WS_FRAG_OFF);
    float* bias = (float*)((char*)d_ws + WS_BIAS_OFF);

    const int nrows = in_sizes[0] / INDIM;

    fno_precompute<<<LAYERS, 1024, 0, stream>>>(fno_wr, fno_wi, projW, wcb);
    fno_pack<<<1, 64, 0, stream>>>(wcb, stemW, headW, stemB, projB, headB, frag, bias);

    const int rows_per_block = 4 * NT * 16;  // 256
    const int nblk = (nrows + rows_per_block - 1) / rows_per_block;
    fno_main<<<nblk, 256, 0, stream>>>(x, frag, bias, out, nrows);
}

// Round 5
// 70.856 us; speedup vs baseline: 2.9416x; 1.0687x over previous
//
#include <hip/hip_runtime.h>
#include <math.h>

#define INDIM 10
#define DIM 32
#define LAYERS 4
#define MODES 17
#define NT 2           // 32-row tiles per wave

// d_ws layout:
//   [0, 16384)        : wc f32 [4][32][32]
//   [16384, 27648)    : frag f16 [11][64][8]   (A-operand fragments, W^T form)
//   [27648, 52224)    : bias f32 [6][4][64][4] (C-operand fragments: stem, 4 layers, head)
#define WS_FRAG_OFF 16384
#define WS_BIAS_OFF 27648

typedef _Float16 f16;
typedef _Float16 f16x8 __attribute__((ext_vector_type(8)));
typedef float f32x4 __attribute__((ext_vector_type(4)));
typedef float f32x16 __attribute__((ext_vector_type(16)));

union BU { f16x8 v; unsigned u[4]; };
union CU { f32x16 v; float4 q[4]; };

// ---------------------------------------------------------------------------
// Fold rfft -> complex mode-mix -> irfft into a real 32x32 matrix per layer,
// added to proj_W.  Wc[l] = M_l + proj_W[l].  (verified round 1)
// ---------------------------------------------------------------------------
__global__ void fno_precompute(const float* __restrict__ wr,
                               const float* __restrict__ wi,
                               const float* __restrict__ projW,
                               float* __restrict__ wc) {
    const int l  = blockIdx.x;
    const int tx = threadIdx.x;
    const int j  = tx & 31;
    const int n  = tx >> 5;

    __shared__ float ct[32], st[32];
    if (tx < 32) {
        float ang = (2.0f * 3.14159265358979323846f / 32.0f) * (float)tx;
        ct[tx] = cosf(ang);
        st[tx] = sinf(ang);
    }
    __syncthreads();

    const float* lwr = wr + l * MODES * MODES;
    const float* lwi = wi + l * MODES * MODES;

    float acc = 0.0f;
    for (int o = 0; o < MODES; ++o) {
        float re = 0.0f, im = 0.0f;
        for (int m = 0; m < MODES; ++m) {
            int t = (m * n) & 31;
            float c = ct[t], s = st[t];
            float a = lwr[m * MODES + o];
            float b = lwi[m * MODES + o];
            re += c * a + s * b;
            im += c * b - s * a;
        }
        int t2 = (o * j) & 31;
        float f = (o == 0 || o == 16) ? 1.0f : 2.0f;
        acc += f * (re * ct[t2] - im * st[t2]);
    }
    acc *= (1.0f / 32.0f);
    wc[(l * DIM + n) * DIM + j] = acc + projW[(l * DIM + n) * DIM + j];
}

// ---------------------------------------------------------------------------
// Pack A-operand fragments (transposed pipeline: A = W^T, layout row=lane&31,
// k = 8*(lane>>5)+e) and C-operand bias fragments (D layout: col=lane&31,
// row-feat = (r&3)+8*(r>>2)+4*(lane>>5)).
// frag idx: 0..7 = layer l*2+kc (k-chunk kc*16..+15); 8 = stem; 9,10 = head.
// bias idx: 0 = stem, 1..4 = layers, 5 = head.
// ---------------------------------------------------------------------------
__global__ void fno_pack(const float* __restrict__ wc,
                         const float* __restrict__ stemW,
                         const float* __restrict__ headW,
                         const float* __restrict__ stemB,
                         const float* __restrict__ projB,
                         const float* __restrict__ headB,
                         f16* __restrict__ frag,
                         float* __restrict__ bias) {
    const int ln = threadIdx.x;  // 64
    const int c  = ln & 31;
    const int G  = ln >> 5;

#pragma unroll
    for (int l = 0; l < LAYERS; ++l)
#pragma unroll
        for (int kc = 0; kc < 2; ++kc)
#pragma unroll
            for (int e = 0; e < 8; ++e) {
                int k = 16 * kc + 8 * G + e;
                frag[((l * 2 + kc) * 64 + ln) * 8 + e] = (f16)wc[(l * DIM + k) * DIM + c];
            }
#pragma unroll
    for (int e = 0; e < 8; ++e) {
        int k = 8 * G + e;
        frag[(8 * 64 + ln) * 8 + e] = (f16)(k < INDIM ? stemW[k * DIM + c] : 0.0f);
    }
#pragma unroll
    for (int kc = 0; kc < 2; ++kc)
#pragma unroll
        for (int e = 0; e < 8; ++e) {
            int k = 16 * kc + 8 * G + e;
            frag[((9 + kc) * 64 + ln) * 8 + e] =
                (f16)(c < INDIM ? headW[k * INDIM + c] : 0.0f);
        }

#pragma unroll
    for (int f = 0; f < 6; ++f)
#pragma unroll
        for (int rq = 0; rq < 4; ++rq)
#pragma unroll
            for (int ri = 0; ri < 4; ++ri) {
                int fr = ri + 8 * rq + 4 * G;   // D-row feature for reg r=4rq+ri
                float v;
                if (f == 0)      v = stemB[fr];
                else if (f <= 4) v = projB[(f - 1) * DIM + fr];
                else             v = (fr < INDIM) ? headB[fr] : 0.0f;
                bias[((f * 4 + rq) * 64 + ln) * 4 + ri] = v;
            }
}

__device__ __forceinline__ float silu_f(float v) {
    return v * __builtin_amdgcn_rcpf(1.0f + __expf(-v));
}

__device__ __forceinline__ unsigned pk2(float a, float b) {
    auto h2 = __builtin_amdgcn_cvt_pkrtz(a, b);   // v_cvt_pkrtz_f16_f32
    return __builtin_bit_cast(unsigned, h2);
}

// D (f32x16, feats per earlier map) -> next-layer B-fragments, entirely in
// registers. One v_permlane32_swap_b32 per dword-pair yields BOTH halves:
//   swap(w0,w2): lanes<32 keep own w0 / receive partner w0 in slot2;
//                lanes>=32 receive partner w2 in slot0 / keep own w2 in slot2.
template <bool SILU>
__device__ __forceinline__ void pack_exchange(const f32x16& D, BU& b0, BU& b1) {
    float s[16];
#pragma unroll
    for (int r = 0; r < 16; ++r) s[r] = SILU ? silu_f(D[r]) : D[r];
    unsigned q0 = pk2(s[0],  s[1]);
    unsigned q1 = pk2(s[2],  s[3]);
    unsigned q2 = pk2(s[4],  s[5]);
    unsigned q3 = pk2(s[6],  s[7]);
    unsigned q4 = pk2(s[8],  s[9]);
    unsigned q5 = pk2(s[10], s[11]);
    unsigned q6 = pk2(s[12], s[13]);
    unsigned q7 = pk2(s[14], s[15]);
    asm("v_permlane32_swap_b32 %0, %1" : "+v"(q0), "+v"(q2));
    asm("v_permlane32_swap_b32 %0, %1" : "+v"(q1), "+v"(q3));
    asm("v_permlane32_swap_b32 %0, %1" : "+v"(q4), "+v"(q6));
    asm("v_permlane32_swap_b32 %0, %1" : "+v"(q5), "+v"(q7));
    b0.u[0] = q0; b0.u[1] = q1; b0.u[2] = q2; b0.u[3] = q3;
    b1.u[0] = q4; b1.u[1] = q5; b1.u[2] = q6; b1.u[3] = q7;
}

// ---------------------------------------------------------------------------
// Main: transposed 32x32 MFMA pipeline, no inter-layer LDS roundtrip.
// Per 32-row tile: stem (1 MFMA) -> 4 x [2 MFMA + silu + reg-exchange]
// -> head (2 MFMA) -> float2 stores. Biases enter as MFMA C-operands.
// ---------------------------------------------------------------------------
__global__ __launch_bounds__(256, 4) void fno_main(
    const float* __restrict__ x,
    const f16*  __restrict__ fragbuf,   // [11][64][8] f16
    const float* __restrict__ biasbuf,  // [6][4][64][4] f32
    float* __restrict__ out,
    int nrows) {

    __shared__ float4 sb[6 * 4 * 64];   // 24 KB, lane-contiguous float4 reads
    {
        const float4* b4 = (const float4*)biasbuf;
        for (int i = threadIdx.x; i < 6 * 4 * 64; i += 256) sb[i] = b4[i];
    }
    __syncthreads();

    const int tid = threadIdx.x;
    const int w   = tid >> 6;
    const int ln  = tid & 63;
    const int c   = ln & 31;
    const int G   = ln >> 5;

    const f16x8* fb = (const f16x8*)fragbuf;
    f16x8 wa[2 * LAYERS];
#pragma unroll
    for (int f = 0; f < 2 * LAYERS; ++f) wa[f] = fb[f * 64 + ln];
    const f16x8 as  = fb[8 * 64 + ln];
    const f16x8 ah0 = fb[9 * 64 + ln];
    const f16x8 ah1 = fb[10 * 64 + ln];

    const long rb0 = (long)blockIdx.x * (4 * NT * 32) + (long)w * (NT * 32);

#pragma unroll
    for (int t = 0; t < NT; ++t) {
        const long rb = rb0 + t * 32;
        const bool ok = (rb + c) < nrows;

        // ---- x -> B-fragment (x^T as B: col=batch c, k=8G+e) ----
        BU bx;
        bx.u[0] = 0; bx.u[1] = 0; bx.u[2] = 0; bx.u[3] = 0;
        const float* xp = x + (rb + c) * INDIM;
        if (ok) {
            if (G == 0) {
                float2 p0 = *(const float2*)(xp + 0);
                float2 p1 = *(const float2*)(xp + 2);
                float2 p2 = *(const float2*)(xp + 4);
                float2 p3 = *(const float2*)(xp + 6);
                bx.u[0] = pk2(p0.x, p0.y);
                bx.u[1] = pk2(p1.x, p1.y);
                bx.u[2] = pk2(p2.x, p2.y);
                bx.u[3] = pk2(p3.x, p3.y);
            } else {
                float2 p4 = *(const float2*)(xp + 8);
                bx.u[0] = pk2(p4.x, p4.y);
            }
        }

        // ---- stem: 1 MFMA, bias via C-operand ----
        CU cs;
        cs.q[0] = sb[(0 * 4 + 0) * 64 + ln];
        cs.q[1] = sb[(0 * 4 + 1) * 64 + ln];
        cs.q[2] = sb[(0 * 4 + 2) * 64 + ln];
        cs.q[3] = sb[(0 * 4 + 3) * 64 + ln];
        f32x16 D = __builtin_amdgcn_mfma_f32_32x32x16_f16(as, bx.v, cs.v, 0, 0, 0);

        BU b0, b1;
        pack_exchange<false>(D, b0, b1);   // stem has no activation

        // ---- 4 fused layers ----
#pragma unroll
        for (int l = 0; l < LAYERS; ++l) {
            CU cl;
            cl.q[0] = sb[((1 + l) * 4 + 0) * 64 + ln];
            cl.q[1] = sb[((1 + l) * 4 + 1) * 64 + ln];
            cl.q[2] = sb[((1 + l) * 4 + 2) * 64 + ln];
            cl.q[3] = sb[((1 + l) * 4 + 3) * 64 + ln];
            f32x16 acc = __builtin_amdgcn_mfma_f32_32x32x16_f16(wa[2 * l],     b0.v, cl.v, 0, 0, 0);
            D          = __builtin_amdgcn_mfma_f32_32x32x16_f16(wa[2 * l + 1], b1.v, acc,  0, 0, 0);
            pack_exchange<true>(D, b0, b1);
        }

        // ---- head: 2 MFMA, bias via C-operand ----
        CU chb;
        chb.q[0] = sb[(5 * 4 + 0) * 64 + ln];
        chb.q[1] = sb[(5 * 4 + 1) * 64 + ln];
        chb.q[2] = sb[(5 * 4 + 2) * 64 + ln];
        chb.q[3] = sb[(5 * 4 + 3) * 64 + ln];
        f32x16 acch = __builtin_amdgcn_mfma_f32_32x32x16_f16(ah0, b0.v, chb.v, 0, 0, 0);
        f32x16 Dh   = __builtin_amdgcn_mfma_f32_32x32x16_f16(ah1, b1.v, acch,  0, 0, 0);

        // ---- store: lane holds batch rb+c, feats (r&3)+8*(r>>2)+4G (<10) ----
        if (ok) {
            float* op = out + (rb + c) * INDIM;
            if (G == 0) {
                *(float2*)(op + 0) = make_float2(Dh[0], Dh[1]);  // f0,f1
                *(float2*)(op + 2) = make_float2(Dh[2], Dh[3]);  // f2,f3
                *(float2*)(op + 8) = make_float2(Dh[4], Dh[5]);  // f8,f9
            } else {
                *(float2*)(op + 4) = make_float2(Dh[0], Dh[1]);  // f4,f5
                *(float2*)(op + 6) = make_float2(Dh[2], Dh[3]);  // f6,f7
            }
        }
    }
}

extern "C" void kernel_launch(void* const* d_in, const int* in_sizes, int n_in,
                              void* d_out, int out_size, void* d_ws, size_t ws_size,
                              hipStream_t stream) {
    const float* x      = (const float*)d_in[0];
    const float* stemW  = (const float*)d_in[1];
    const float* stemB  = (const float*)d_in[2];
    const float* fno_wr = (const float*)d_in[3];
    const float* fno_wi = (const float*)d_in[4];
    const float* projW  = (const float*)d_in[5];
    const float* projB  = (const float*)d_in[6];
    const float* headW  = (const float*)d_in[7];
    const float* headB  = (const float*)d_in[8];
    float* out = (float*)d_out;

    float* wcb  = (float*)d_ws;
    f16*   frag = (f16*)((char*)d_ws + WS_FRAG_OFF);
    float* bias = (float*)((char*)d_ws + WS_BIAS_OFF);

    const int nrows = in_sizes[0] / INDIM;

    fno_precompute<<<LAYERS, 1024, 0, stream>>>(fno_wr, fno_wi, projW, wcb);
    fno_pack<<<1, 64, 0, stream>>>(wcb, stemW, headW, stemB, projB, headB, frag, bias);

    const int rows_per_block = 4 * NT * 32;  // 256
    const int nblk = (nrows + rows_per_block - 1) / rows_per_block;
    fno_main<<<nblk, 256, 0, stream>>>(x, frag, bias, out, nrows);
}

// Round 8
// 67.644 us; speedup vs baseline: 3.0813x; 1.0475x over previous
//
#include <hip/hip_runtime.h>
#include <math.h>

#define INDIM 10
#define DIM 32
#define LAYERS 4
#define MODES 17

// d_ws layout:
//   [0, 16384)        : wc f32 [4][32][32]
//   [16384, 27648)    : frag f16 [11][64][8]  (A-operand fragments, W^T form)
//   [27648, 28416)    : bias2 f32 [6][32]     (compact per-stage bias tables)
#define WS_FRAG_OFF 16384
#define WS_BIAS_OFF 27648

typedef _Float16 f16;
typedef _Float16 f16x8 __attribute__((ext_vector_type(8)));
typedef float f32x16 __attribute__((ext_vector_type(16)));
typedef unsigned u32x2 __attribute__((ext_vector_type(2)));

union BU { f16x8 v; unsigned u[4]; };
union CU { f32x16 v; float4 q[4]; };

// ---------------------------------------------------------------------------
// Fold rfft -> complex mode-mix -> irfft into a real 32x32 matrix per layer,
// added to proj_W.  Wc[l] = M_l + proj_W[l].  (verified round 1)
// ---------------------------------------------------------------------------
__global__ void fno_precompute(const float* __restrict__ wr,
                               const float* __restrict__ wi,
                               const float* __restrict__ projW,
                               float* __restrict__ wc) {
    const int l  = blockIdx.x;
    const int tx = threadIdx.x;
    const int j  = tx & 31;
    const int n  = tx >> 5;

    __shared__ float ct[32], st[32];
    if (tx < 32) {
        float ang = (2.0f * 3.14159265358979323846f / 32.0f) * (float)tx;
        ct[tx] = cosf(ang);
        st[tx] = sinf(ang);
    }
    __syncthreads();

    const float* lwr = wr + l * MODES * MODES;
    const float* lwi = wi + l * MODES * MODES;

    float acc = 0.0f;
    for (int o = 0; o < MODES; ++o) {
        float re = 0.0f, im = 0.0f;
        for (int m = 0; m < MODES; ++m) {
            int t = (m * n) & 31;
            float c = ct[t], s = st[t];
            float a = lwr[m * MODES + o];
            float b = lwi[m * MODES + o];
            re += c * a + s * b;
            im += c * b - s * a;
        }
        int t2 = (o * j) & 31;
        float f = (o == 0 || o == 16) ? 1.0f : 2.0f;
        acc += f * (re * ct[t2] - im * st[t2]);
    }
    acc *= (1.0f / 32.0f);
    wc[(l * DIM + n) * DIM + j] = acc + projW[(l * DIM + n) * DIM + j];
}

// ---------------------------------------------------------------------------
// Pack A-operand fragments (A = W^T: row=lane&31, k=8*(lane>>5)+e) and the
// compact per-stage bias tables bias2[6][32] (stem, 4 layers, head).
// frag idx: 0..7 = layer l*2+kc; 8 = stem; 9,10 = head k-chunks.
// ---------------------------------------------------------------------------
__global__ void fno_pack(const float* __restrict__ wc,
                         const float* __restrict__ stemW,
                         const float* __restrict__ headW,
                         const float* __restrict__ stemB,
                         const float* __restrict__ projB,
                         const float* __restrict__ headB,
                         f16* __restrict__ frag,
                         float* __restrict__ bias2) {
    const int ln = threadIdx.x;  // 64
    const int c  = ln & 31;
    const int G  = ln >> 5;

#pragma unroll
    for (int l = 0; l < LAYERS; ++l)
#pragma unroll
        for (int kc = 0; kc < 2; ++kc)
#pragma unroll
            for (int e = 0; e < 8; ++e) {
                int k = 16 * kc + 8 * G + e;
                frag[((l * 2 + kc) * 64 + ln) * 8 + e] = (f16)wc[(l * DIM + k) * DIM + c];
            }
#pragma unroll
    for (int e = 0; e < 8; ++e) {
        int k = 8 * G + e;
        frag[(8 * 64 + ln) * 8 + e] = (f16)(k < INDIM ? stemW[k * DIM + c] : 0.0f);
    }
#pragma unroll
    for (int kc = 0; kc < 2; ++kc)
#pragma unroll
        for (int e = 0; e < 8; ++e) {
            int k = 16 * kc + 8 * G + e;
            frag[((9 + kc) * 64 + ln) * 8 + e] =
                (f16)(c < INDIM ? headW[k * INDIM + c] : 0.0f);
        }

    if (ln < 32) {
#pragma unroll
        for (int f = 0; f < 6; ++f) {
            float v;
            if (f == 0)      v = stemB[ln];
            else if (f <= 4) v = projB[(f - 1) * DIM + ln];
            else             v = (ln < INDIM) ? headB[ln] : 0.0f;
            bias2[f * 32 + ln] = v;
        }
    }
}

__device__ __forceinline__ float silu_f(float v) {
    return v * __builtin_amdgcn_rcpf(1.0f + __expf(-v));
}

__device__ __forceinline__ unsigned pk2(float a, float b) {
    auto h2 = __builtin_amdgcn_cvt_pkrtz(a, b);   // v_cvt_pkrtz_f16_f32
    return __builtin_bit_cast(unsigned, h2);
}

// Compiler-modeled lane<32 <-> lane>=32 exchange. Using the builtin (instead
// of raw asm) lets the scheduler/hazard-recognizer order it correctly against
// the MFMAs that consume its outputs (rule-#18 class hazard with plain asm).
__device__ __forceinline__ void pswap(unsigned& a, unsigned& b) {
#if __has_builtin(__builtin_amdgcn_permlane32_swap)
    u32x2 r = __builtin_amdgcn_permlane32_swap(a, b, false, false);
    a = r[0];
    b = r[1];
#else
    asm("v_permlane32_swap_b32 %0, %1" : "+v"(a), "+v"(b));
    __builtin_amdgcn_sched_barrier(0);   // pin: nothing moves across the swap
#endif
}

// D (f32x16) -> next-layer B-fragments, entirely in registers.
// One permlane32_swap per dword-pair yields both halves (verified round 5).
template <bool SILU>
__device__ __forceinline__ void pack_exchange(const f32x16& D, BU& b0, BU& b1) {
    float s[16];
#pragma unroll
    for (int r = 0; r < 16; ++r) s[r] = SILU ? silu_f(D[r]) : D[r];
    unsigned q0 = pk2(s[0],  s[1]);
    unsigned q1 = pk2(s[2],  s[3]);
    unsigned q2 = pk2(s[4],  s[5]);
    unsigned q3 = pk2(s[6],  s[7]);
    unsigned q4 = pk2(s[8],  s[9]);
    unsigned q5 = pk2(s[10], s[11]);
    unsigned q6 = pk2(s[12], s[13]);
    unsigned q7 = pk2(s[14], s[15]);
    pswap(q0, q2);
    pswap(q1, q3);
    pswap(q4, q6);
    pswap(q5, q7);
    b0.u[0] = q0; b0.u[1] = q1; b0.u[2] = q2; b0.u[3] = q3;
    b1.u[0] = q4; b1.u[1] = q5; b1.u[2] = q6; b1.u[3] = q7;
}

// C-operand bias fragment from the 768B LDS table (half-wave broadcast reads).
__device__ __forceinline__ f32x16 ld_bias(const float* sbias, int stage, int G) {
    CU c;
#pragma unroll
    for (int rq = 0; rq < 4; ++rq)
        c.q[rq] = *(const float4*)&sbias[stage * 32 + rq * 8 + G * 4];
    return c.v;
}

__device__ __forceinline__ BU load_x(const float* __restrict__ x, long rb,
                                     int c, int G, int nrows) {
    BU b;
    b.u[0] = 0; b.u[1] = 0; b.u[2] = 0; b.u[3] = 0;
    const long r = rb + c;
    if (r < nrows) {
        const float* xp = x + r * INDIM;
        if (G == 0) {
            float2 p0 = *(const float2*)(xp + 0);
            float2 p1 = *(const float2*)(xp + 2);
            float2 p2 = *(const float2*)(xp + 4);
            float2 p3 = *(const float2*)(xp + 6);
            b.u[0] = pk2(p0.x, p0.y);
            b.u[1] = pk2(p1.x, p1.y);
            b.u[2] = pk2(p2.x, p2.y);
            b.u[3] = pk2(p3.x, p3.y);
        } else {
            float2 p4 = *(const float2*)(xp + 8);
            b.u[0] = pk2(p4.x, p4.y);
        }
    }
    return b;
}

__device__ __forceinline__ void store_o(float* __restrict__ out, long rb,
                                        int c, int G, int nrows, const f32x16& Dh) {
    const long r = rb + c;
    if (r < nrows) {
        float* op = out + r * INDIM;
        if (G == 0) {
            *(float2*)(op + 0) = make_float2(Dh[0], Dh[1]);  // f0,f1
            *(float2*)(op + 2) = make_float2(Dh[2], Dh[3]);  // f2,f3
            *(float2*)(op + 8) = make_float2(Dh[4], Dh[5]);  // f8,f9
        } else {
            *(float2*)(op + 4) = make_float2(Dh[0], Dh[1]);  // f4,f5
            *(float2*)(op + 6) = make_float2(Dh[2], Dh[3]);  // f6,f7
        }
    }
}

// ---------------------------------------------------------------------------
// Main: transposed 32x32 MFMA pipeline, DUAL independent 32-row chains per
// wave interleaved stage-by-stage (ILP: chain B's silu issues under chain A's
// MFMA latency). Biases enter as shared MFMA C-operands from a 768B table.
// launch_bounds (256,3): ~168-VGPR cap fits dual-chain state without spills.
// ---------------------------------------------------------------------------
__global__ __launch_bounds__(256, 3) void fno_main(
    const float* __restrict__ x,
    const f16*  __restrict__ fragbuf,   // [11][64][8] f16
    const float* __restrict__ bias2,    // [6][32] f32
    float* __restrict__ out,
    int nrows) {

    __shared__ __align__(16) float sbias[6 * 32];
    if (threadIdx.x < 6 * 32) sbias[threadIdx.x] = bias2[threadIdx.x];
    __syncthreads();

    const int tid = threadIdx.x;
    const int w   = tid >> 6;
    const int ln  = tid & 63;
    const int c   = ln & 31;
    const int G   = ln >> 5;

    const f16x8* fb = (const f16x8*)fragbuf;
    f16x8 wa[2 * LAYERS];
#pragma unroll
    for (int f = 0; f < 2 * LAYERS; ++f) wa[f] = fb[f * 64 + ln];
    const f16x8 as  = fb[8 * 64 + ln];
    const f16x8 ah0 = fb[9 * 64 + ln];
    const f16x8 ah1 = fb[10 * 64 + ln];

    const long rbA = (long)blockIdx.x * 256 + (long)w * 64;
    const long rbB = rbA + 32;

    // ---- stem: shared C-frag, two independent MFMAs ----
    BU bxA = load_x(x, rbA, c, G, nrows);
    BU bxB = load_x(x, rbB, c, G, nrows);
    const f32x16 csv = ld_bias(sbias, 0, G);
    f32x16 DA = __builtin_amdgcn_mfma_f32_32x32x16_f16(as, bxA.v, csv, 0, 0, 0);
    f32x16 DB = __builtin_amdgcn_mfma_f32_32x32x16_f16(as, bxB.v, csv, 0, 0, 0);

    BU a0, a1, b0, b1;
    pack_exchange<false>(DA, a0, a1);
    pack_exchange<false>(DB, b0, b1);

    // ---- 4 fused layers, dual chains ----
#pragma unroll
    for (int l = 0; l < LAYERS; ++l) {
        const f32x16 clv = ld_bias(sbias, 1 + l, G);
        f32x16 tA = __builtin_amdgcn_mfma_f32_32x32x16_f16(wa[2 * l], a0.v, clv, 0, 0, 0);
        f32x16 tB = __builtin_amdgcn_mfma_f32_32x32x16_f16(wa[2 * l], b0.v, clv, 0, 0, 0);
        tA = __builtin_amdgcn_mfma_f32_32x32x16_f16(wa[2 * l + 1], a1.v, tA, 0, 0, 0);
        tB = __builtin_amdgcn_mfma_f32_32x32x16_f16(wa[2 * l + 1], b1.v, tB, 0, 0, 0);
        pack_exchange<true>(tA, a0, a1);
        pack_exchange<true>(tB, b0, b1);
    }

    // ---- head, dual chains ----
    const f32x16 hv = ld_bias(sbias, 5, G);
    f32x16 HA = __builtin_amdgcn_mfma_f32_32x32x16_f16(ah0, a0.v, hv, 0, 0, 0);
    f32x16 HB = __builtin_amdgcn_mfma_f32_32x32x16_f16(ah0, b0.v, hv, 0, 0, 0);
    HA = __builtin_amdgcn_mfma_f32_32x32x16_f16(ah1, a1.v, HA, 0, 0, 0);
    HB = __builtin_amdgcn_mfma_f32_32x32x16_f16(ah1, b1.v, HB, 0, 0, 0);

    store_o(out, rbA, c, G, nrows, HA);
    store_o(out, rbB, c, G, nrows, HB);
}

extern "C" void kernel_launch(void* const* d_in, const int* in_sizes, int n_in,
                              void* d_out, int out_size, void* d_ws, size_t ws_size,
                              hipStream_t stream) {
    const float* x      = (const float*)d_in[0];
    const float* stemW  = (const float*)d_in[1];
    const float* stemB  = (const float*)d_in[2];
    const float* fno_wr = (const float*)d_in[3];
    const float* fno_wi = (const float*)d_in[4];
    const float* projW  = (const float*)d_in[5];
    const float* projB  = (const float*)d_in[6];
    const float* headW  = (const float*)d_in[7];
    const float* headB  = (const float*)d_in[8];
    float* out = (float*)d_out;

    float* wcb   = (float*)d_ws;
    f16*   frag  = (f16*)((char*)d_ws + WS_FRAG_OFF);
    float* bias2 = (float*)((char*)d_ws + WS_BIAS_OFF);

    const int nrows = in_sizes[0] / INDIM;

    fno_precompute<<<LAYERS, 1024, 0, stream>>>(fno_wr, fno_wi, projW, wcb);
    fno_pack<<<1, 64, 0, stream>>>(wcb, stemW, headW, stemB, projB, headB, frag, bias2);

    const int rows_per_block = 256;   // 4 waves x 2 chains x 32 rows
    const int nblk = (nrows + rows_per_block - 1) / rows_per_block;
    fno_main<<<nblk, 256, 0, stream>>>(x, frag, bias2, out, nrows);
}